// Round 1
// baseline (4449.146 us; speedup 1.0000x reference)
//
#include <hip/hip_runtime.h>
#include <math.h>

// Problem constants
#define DIMS   6
#define NGEO   20
#define NPHI   27
#define NEXPERT 540
#define MPTS   256
#define NTEST  1024
#define NMAT   560          // experts + baselines
#define JIT    1e-4f
#define USTRIDE 33280       // packed padded upper-triangular floats per matrix
#define L2E    1.44269504088896340736f

// Row j of U (cols j..255) starts at uoff(j); each row padded to 4-float multiple.
__device__ __forceinline__ int uoff(int j){
    int m = j >> 2, r = j & 3;
    return 1024*m - 8*m*(m-1) + r*(256 - 4*m);
}

// ---------------------------------------------------------------------------
// Kernel 1: 2-level GMM hard routing (fp64 to match np reference argmax)
// ---------------------------------------------------------------------------
__global__ __launch_bounds__(256)
void route_kernel(const float* __restrict__ Xt, const float* __restrict__ sm,
                  const float* __restrict__ ss,
                  const float* __restrict__ gm, const float* __restrict__ glv,
                  const float* __restrict__ glw,
                  const float* __restrict__ pm, const float* __restrict__ plv,
                  const float* __restrict__ plw,
                  int* __restrict__ e_idx, int* __restrict__ g_idx)
{
    int n = blockIdx.x*256 + threadIdx.x;
    if (n >= NTEST) return;
    double xs[DIMS];
    #pragma unroll
    for (int d=0; d<DIMS; d++)
        xs[d] = ((double)Xt[n*DIMS+d] - (double)sm[d]) / (double)ss[d];
    const double cst = (double)DIMS * 1.8378770664093453;  // D*log(2*pi)

    int bg = 0; double best = -1e300;
    for (int j=0; j<NGEO; j++){
        double s = 0.0;
        #pragma unroll
        for (int d=0; d<DIMS; d++){
            double lv = (double)glv[j*DIMS+d];
            double df = xs[d] - (double)gm[j*DIMS+d];
            s += lv + df*df*exp(-lv);
        }
        double lp = (double)glw[j] - 0.5*(s + cst);
        if (lp > best){ best = lp; bg = j; }
    }
    int bk = 0; best = -1e300;
    for (int k=0; k<NPHI; k++){
        double s = 0.0;
        int o = (bg*NPHI + k)*DIMS;
        #pragma unroll
        for (int d=0; d<DIMS; d++){
            double lv = (double)plv[o+d];
            double df = xs[d] - (double)pm[o+d];
            s += lv + df*df*exp(-lv);
        }
        double lp = (double)plw[bg*NPHI+k] - 0.5*(s + cst);
        if (lp > best){ best = lp; bk = k; }
    }
    e_idx[n] = bg*NPHI + bk;
    g_idx[n] = bg;
}

// ---------------------------------------------------------------------------
// Kernel 2: per-matrix build K, Cholesky (U = L^T packed upper in global ws),
//           and v = L^-1 y.  One block (256 threads) per matrix.
// ---------------------------------------------------------------------------
__global__ __launch_bounds__(256)
void chol_kernel(const float* __restrict__ X_exp, const float* __restrict__ Y_exp,
                 const float* __restrict__ X_base, const float* __restrict__ Y_base,
                 const float* __restrict__ lls_e, const float* __restrict__ los_e,
                 const float* __restrict__ lno_e,
                 const float* __restrict__ lls_b, const float* __restrict__ los_b,
                 const float* __restrict__ lno_b,
                 float* __restrict__ Uws, float* __restrict__ Vws)
{
    __shared__ float Xs[256*8];        // training points, row-padded to 8
    __shared__ float Ps[32*260];       // factored panel: Ps[c][t] = U[32s+c][t]
    __shared__ float cb[2][32];        // column broadcast (double-buffered)

    int b = blockIdx.x, t = threadIdx.x;
    const float *Xtr, *Ytr;
    float lls, los, lno;
    if (b < NEXPERT){
        Xtr = X_exp + b*(MPTS*DIMS); Ytr = Y_exp + b*MPTS;
        lls = lls_e[b]; los = los_e[b]; lno = lno_e[b];
    } else {
        int g = b - NEXPERT;
        Xtr = X_base + g*(MPTS*DIMS); Ytr = Y_base + g*MPTS;
        lls = lls_b[g]; los = los_b[g]; lno = lno_b[g];
    }
    float ls2 = expf(2.f*lls);
    float os  = expf(los);
    float nv  = expf(lno) + JIT;
    float c1  = -0.5f*L2E/ls2;
    float* Ug = Uws + (size_t)b*USTRIDE;

    // stage X into LDS (padded stride 8)
    for (int i=t; i<MPTS*DIMS; i+=256){ int r=i/DIMS, d=i-r*DIMS; Xs[r*8+d]=Xtr[i]; }
    for (int i=t; i<MPTS*2;   i+=256){ int r=i>>1; Xs[r*8+6+(i&1)]=0.f; }
    __syncthreads();

    // build K: thread t builds row t of U (cols t..255)
    {
        float x0=Xs[t*8+0], x1=Xs[t*8+1], x2=Xs[t*8+2];
        float x3=Xs[t*8+3], x4=Xs[t*8+4], x5=Xs[t*8+5];
        int ro = uoff(t), len = 256 - t;
        for (int ii=0; ii<len; ii++){
            int i = t + ii;
            float4 a  = *(const float4*)&Xs[i*8];
            float4 b2 = *(const float4*)&Xs[i*8+4];
            float d0=x0-a.x, d1=x1-a.y, d2=x2-a.z, d3=x3-a.w, d4=x4-b2.x, d5=x5-b2.y;
            float dd = d0*d0+d1*d1+d2*d2+d3*d3+d4*d4+d5*d5;
            float u = os*exp2f(c1*dd);
            if (ii==0) u += nv;
            Ug[ro+ii] = u;
        }
        int lp = (len+3)&~3;
        for (int ii=len; ii<lp; ii++) Ug[ro+ii] = 0.f;
    }
    __syncthreads();

    // blocked right-looking Cholesky, panel width 32, panel in registers:
    // thread t owns panel column t:  p[c] = U[32s+c][t]
    for (int s=0; s<8; s++){
        int base = 32*s;
        float p[32];
        {
            int offc = uoff(base);
            #pragma unroll
            for (int c=0; c<32; c++){
                int j = base+c, d = t-j;
                float v = 0.f;
                if (d >= 0) v = Ug[offc + d];
                p[c] = v;
                offc += (259-j)&~3;
            }
        }
        // factor 32 columns (1 barrier per column)
        #pragma unroll
        for (int c=0; c<32; c++){
            int ph = c & 1;
            int lk = t - base;
            if (lk >= c && lk < 32) cb[ph][lk] = p[c];   // unscaled column entries
            __syncthreads();
            float piv = cb[ph][c];
            float inv = 1.f/piv;
            float irs = rsqrtf(piv);
            float f   = p[c]*inv;
            #pragma unroll
            for (int k=c+1; k<32; k++) p[k] -= f*cb[ph][k];
            p[c] *= irs;
        }
        // write panel back (global + LDS for syrk)
        {
            int offc = uoff(base);
            #pragma unroll
            for (int c=0; c<32; c++){
                int j = base+c, d = t-j;
                if (d >= 0){ Ug[offc + d] = p[c]; Ps[c*260 + t] = p[c]; }
                offc += (259-j)&~3;
            }
        }
        __syncthreads();
        // trailing syrk: C[k][i] -= sum_c U[base+c][k]*U[base+c][i], 8x8 reg tiles
        if (s < 7){
            int tb = base + 32, nt = 256 - tb, ntile = nt >> 3;
            int ntp = ntile*(ntile+1)/2;
            for (int tp = t; tp < ntp; tp += 256){
                int ti = (int)((sqrtf(8.f*(float)tp + 1.f) - 1.f)*0.5f);
                while ((ti+1)*(ti+2)/2 <= tp) ti++;
                while (ti*(ti+1)/2 > tp) ti--;
                int tj = tp - ti*(ti+1)/2;
                int I0 = tb + ti*8, K0 = tb + tj*8;
                float acc[8][8];
                int roK[8];
                #pragma unroll
                for (int kk=0; kk<8; kk++) roK[kk] = uoff(K0+kk);
                #pragma unroll
                for (int kk=0; kk<8; kk++){
                    int kr = K0+kk;
                    #pragma unroll
                    for (int ii=0; ii<8; ii++){
                        int ic = I0+ii;
                        acc[kk][ii] = (ic >= kr) ? Ug[roK[kk] + ic - kr] : 0.f;
                    }
                }
                #pragma unroll
                for (int c=0; c<32; c++){
                    float4 a0 = *(const float4*)&Ps[c*260 + I0];
                    float4 a1 = *(const float4*)&Ps[c*260 + I0 + 4];
                    float4 b0 = *(const float4*)&Ps[c*260 + K0];
                    float4 b1 = *(const float4*)&Ps[c*260 + K0 + 4];
                    float av[8] = {a0.x,a0.y,a0.z,a0.w,a1.x,a1.y,a1.z,a1.w};
                    float bv[8] = {b0.x,b0.y,b0.z,b0.w,b1.x,b1.y,b1.z,b1.w};
                    #pragma unroll
                    for (int kk=0; kk<8; kk++)
                        #pragma unroll
                        for (int ii=0; ii<8; ii++)
                            acc[kk][ii] -= bv[kk]*av[ii];
                }
                #pragma unroll
                for (int kk=0; kk<8; kk++){
                    int kr = K0+kk;
                    #pragma unroll
                    for (int ii=0; ii<8; ii++){
                        int ic = I0+ii;
                        if (ic >= kr) Ug[roK[kk] + ic - kr] = acc[kk][ii];
                    }
                }
            }
        }
        __syncthreads();
    }

    // v = L^-1 y  (forward solve, wave 0 only; L columns = U rows, coalesced)
    if (t < 64){
        int l = t;
        float z[4], rd[4];
        #pragma unroll
        for (int q=0; q<4; q++){
            z[q]  = Ytr[64*q + l];
            rd[q] = 1.f/Ug[uoff(64*q + l)];
        }
        int offj = 0;
        #pragma unroll
        for (int q=0; q<4; q++){
            for (int j2=0; j2<64; j2++){
                int j = 64*q + j2;
                float zf = __shfl(z[q], j2) * __shfl(rd[q], j2);
                if (l == j2) z[q] = zf;
                #pragma unroll
                for (int r=q; r<4; r++){
                    int dd = 64*(r-q) + (l - j2);
                    int dc = dd > 0 ? dd : 0;
                    float uv = Ug[offj + dc];
                    if (dd > 0) z[r] -= uv*zf;
                }
                offj += (259-j)&~3;
            }
        }
        #pragma unroll
        for (int q=0; q<4; q++) Vws[b*256 + 64*q + l] = z[q];
    }
}

// ---------------------------------------------------------------------------
// Kernel 3: per-point prediction (one wave per (point, side)) + rBCM combine
// ---------------------------------------------------------------------------
__global__ __launch_bounds__(256)
void predict_kernel(const float* __restrict__ Xt,
                    const float* __restrict__ X_exp, const float* __restrict__ X_base,
                    const float* __restrict__ lls_e, const float* __restrict__ los_e,
                    const float* __restrict__ lno_e,
                    const float* __restrict__ lls_b, const float* __restrict__ los_b,
                    const float* __restrict__ lno_b,
                    const int* __restrict__ nullmask,
                    const float* __restrict__ Uws, const float* __restrict__ Vws,
                    const int* __restrict__ e_idx, const int* __restrict__ g_idx,
                    float* __restrict__ out)
{
    __shared__ float res[4][4];   // per local wave: mu, var, prior
    int lw = threadIdx.x >> 6, l = threadIdx.x & 63;
    int wt = blockIdx.x*4 + lw, n = wt >> 1, side = wt & 1;

    int bidx; const float* Xtr; float lls, los, lno;
    if (side == 0){
        int ee = e_idx[n]; bidx = ee; Xtr = X_exp + ee*(MPTS*DIMS);
        lls = lls_e[ee]; los = los_e[ee]; lno = lno_e[ee];
    } else {
        int g = g_idx[n]; bidx = NEXPERT + g; Xtr = X_base + g*(MPTS*DIMS);
        lls = lls_b[g]; los = los_b[g]; lno = lno_b[g];
    }
    float ls2 = expf(2.f*lls), os = expf(los), nv = expf(lno) + JIT;
    float c1 = -0.5f*L2E/ls2;
    float xt[DIMS];
    #pragma unroll
    for (int d=0; d<DIMS; d++) xt[d] = Xt[n*DIMS + d];

    const float* Ug = Uws + (size_t)bidx*USTRIDE;
    const float* vv = Vws + bidx*256;

    // k* into registers (rows 64q+l), plus diag reciprocals
    float z[4], rd[4];
    #pragma unroll
    for (int q=0; q<4; q++){
        int m = 64*q + l;
        float d2 = 0.f;
        #pragma unroll
        for (int d=0; d<DIMS; d++){ float df = xt[d]-Xtr[m*DIMS+d]; d2 += df*df; }
        z[q]  = os*exp2f(c1*d2);
        rd[q] = 1.f/Ug[uoff(m)];
    }
    // w = L^-1 k*  (forward solve; L columns = U rows, coalesced loads)
    int offj = 0;
    #pragma unroll
    for (int q=0; q<4; q++){
        #pragma unroll 4
        for (int j2=0; j2<64; j2++){
            int j = 64*q + j2;
            float zf = __shfl(z[q], j2) * __shfl(rd[q], j2);
            if (l == j2) z[q] = zf;
            #pragma unroll
            for (int r=q; r<4; r++){
                int dd = 64*(r-q) + (l - j2);
                int dc = dd > 0 ? dd : 0;
                float uv = Ug[offj + dc];
                if (dd > 0) z[r] -= uv*zf;
            }
            offj += (259-j)&~3;
        }
    }
    // q = w.w ; mu = w.v
    float qq = 0.f, mu = 0.f;
    #pragma unroll
    for (int q=0; q<4; q++){ qq += z[q]*z[q]; mu += z[q]*vv[64*q + l]; }
    #pragma unroll
    for (int o=32; o>0; o>>=1){ qq += __shfl_xor(qq, o); mu += __shfl_xor(mu, o); }
    if (l == 0){
        res[lw][0] = mu;
        res[lw][1] = fmaxf(os - qq, JIT) + nv;   // predictive var incl noise
        res[lw][2] = os + nv;                    // prior
    }
    __syncthreads();
    if (threadIdx.x < 2){
        int pp = threadIdx.x, n2 = blockIdx.x*2 + pp;
        float mu_e = res[2*pp][0],   var_e = res[2*pp][1],   pr_e = res[2*pp][2];
        float mu_b = res[2*pp+1][0], var_b = res[2*pp+1][1], pr_b = res[2*pp+1][2];
        int ee = e_idx[n2];
        float be = (nullmask[ee] == 0) ? 0.f
                 : fmaxf(0.5f*(logf(pr_e) - logf(var_e)), 0.f);
        float bb = fmaxf(0.5f*(logf(pr_b) - logf(var_b)), 0.f);
        float prec = be/var_e + bb/var_b + (1.f - be - bb)/pr_b;
        prec = fmaxf(prec, 1e-6f);
        out[n2]        = (be*mu_e/var_e + bb*mu_b/var_b)/prec;
        out[NTEST + n2] = 1.f/prec;
    }
}

// ---------------------------------------------------------------------------
extern "C" void kernel_launch(void* const* d_in, const int* in_sizes, int n_in,
                              void* d_out, int out_size, void* d_ws, size_t ws_size,
                              hipStream_t stream)
{
    const float* X_test  = (const float*)d_in[0];
    const float* X_exp   = (const float*)d_in[1];
    const float* Y_exp   = (const float*)d_in[2];
    const float* X_base  = (const float*)d_in[3];
    const float* Y_base  = (const float*)d_in[4];
    const float* lls_e   = (const float*)d_in[5];
    const float* los_e   = (const float*)d_in[6];
    const float* lno_e   = (const float*)d_in[7];
    const float* lls_b   = (const float*)d_in[8];
    const float* los_b   = (const float*)d_in[9];
    const float* lno_b   = (const float*)d_in[10];
    const float* sm      = (const float*)d_in[11];
    const float* ss      = (const float*)d_in[12];
    const float* gm      = (const float*)d_in[13];
    const float* glv     = (const float*)d_in[14];
    const float* glw     = (const float*)d_in[15];
    const float* pm      = (const float*)d_in[16];
    const float* plv     = (const float*)d_in[17];
    const float* plw     = (const float*)d_in[18];
    const int*   nmask   = (const int*)d_in[19];

    float* Uws = (float*)d_ws;                       // NMAT*USTRIDE floats (74.5 MB)
    float* Vws = Uws + (size_t)NMAT*USTRIDE;         // NMAT*256 floats
    int*   e_idx = (int*)(Vws + (size_t)NMAT*256);   // NTEST ints
    int*   g_idx = e_idx + NTEST;                    // NTEST ints
    float* out = (float*)d_out;

    route_kernel<<<dim3(NTEST/256), dim3(256), 0, stream>>>(
        X_test, sm, ss, gm, glv, glw, pm, plv, plw, e_idx, g_idx);
    chol_kernel<<<dim3(NMAT), dim3(256), 0, stream>>>(
        X_exp, Y_exp, X_base, Y_base,
        lls_e, los_e, lno_e, lls_b, los_b, lno_b, Uws, Vws);
    predict_kernel<<<dim3(NTEST/2), dim3(256), 0, stream>>>(
        X_test, X_exp, X_base,
        lls_e, los_e, lno_e, lls_b, los_b, lno_b,
        nmask, Uws, Vws, e_idx, g_idx, out);
}